// Round 6
// baseline (458.981 us; speedup 1.0000x reference)
//
#include <hip/hip_runtime.h>
#include <hip/hip_bf16.h>
#include <stdint.h>

#define B_SZ 8192
#define D_SZ 1024
#define O_SZ 1024
#define E_SZ 8

#define BM 256
#define BN 128
#define BK 64
#define NT 128  // virtual K-steps: E_SZ * (D_SZ / BK)

typedef __bf16 bf16_t;
typedef __bf16 bf16x8 __attribute__((ext_vector_type(8)));
typedef __bf16 bf16x4 __attribute__((ext_vector_type(4)));
typedef float  f32x4  __attribute__((ext_vector_type(4)));

// ---------------- merged prep: gating+cvt (blocks 0..2047) | We transpose (2048..4095) ----------------
__global__ __launch_bounds__(256) void prep_kernel(
    const float* __restrict__ x, const float* __restrict__ Wg,
    const float* __restrict__ bg, const float* __restrict__ We,
    float* __restrict__ gates, bf16_t* __restrict__ xb,
    bf16_t* __restrict__ wet) {
  __shared__ float tile[64][65];
  const int bid = blockIdx.x;
  if (bid < 2048) {
    // ---- gating: softmax(x @ Wg + bg) fused with x fp32->bf16 ----
    const int w = threadIdx.x >> 6, lane = threadIdx.x & 63;
    const int b = bid * 4 + w;
    const float4* xr = (const float4*)(x + (size_t)b * D_SZ);
    bf16x4* xbr = (bf16x4*)(xb + (size_t)b * D_SZ);
    float acc[8];
#pragma unroll
    for (int e = 0; e < 8; ++e) acc[e] = 0.f;
#pragma unroll 1
    for (int it = 0; it < 4; ++it) {
      int d4 = it * 64 + lane;  // float4 index; d = d4*4
      float4 v = xr[d4];
      bf16x4 ob;
      ob[0] = (bf16_t)v.x; ob[1] = (bf16_t)v.y;
      ob[2] = (bf16_t)v.z; ob[3] = (bf16_t)v.w;
      xbr[d4] = ob;
      const float4* wr = (const float4*)(Wg + (size_t)d4 * 32);  // 4 rows x 8
      float xs[4] = {v.x, v.y, v.z, v.w};
#pragma unroll
      for (int rr = 0; rr < 4; ++rr) {
        float4 wa = wr[rr * 2], wb = wr[rr * 2 + 1];
        acc[0] += xs[rr] * wa.x; acc[1] += xs[rr] * wa.y;
        acc[2] += xs[rr] * wa.z; acc[3] += xs[rr] * wa.w;
        acc[4] += xs[rr] * wb.x; acc[5] += xs[rr] * wb.y;
        acc[6] += xs[rr] * wb.z; acc[7] += xs[rr] * wb.w;
      }
    }
#pragma unroll
    for (int off = 32; off >= 1; off >>= 1) {
#pragma unroll
      for (int e = 0; e < 8; ++e) acc[e] += __shfl_xor(acc[e], off, 64);
    }
    if (lane == 0) {
#pragma unroll
      for (int e = 0; e < 8; ++e) acc[e] += bg[e];
      float m = acc[0];
#pragma unroll
      for (int e = 1; e < 8; ++e) m = fmaxf(m, acc[e]);
      float s = 0.f, ex[8];
#pragma unroll
      for (int e = 0; e < 8; ++e) { ex[e] = __expf(acc[e] - m); s += ex[e]; }
      float inv = 1.0f / s;
      float* gr = gates + (size_t)b * 8;
#pragma unroll
      for (int e = 0; e < 8; ++e) gr[e] = ex[e] * inv;
    }
  } else {
    // ---- We [E,D,O] fp32 -> WeT [E,O,D] bf16 ----
    const int bt = bid - 2048;
    const int e = bt >> 8;
    const int d0 = ((bt >> 4) & 15) * 64, o0 = (bt & 15) * 64;
    const int tx = threadIdx.x & 63, ty = threadIdx.x >> 6;
    const float* src = We + (size_t)e * D_SZ * O_SZ;
#pragma unroll
    for (int i = 0; i < 16; ++i) {
      int d = ty + i * 4;
      tile[d][tx] = src[(size_t)(d0 + d) * O_SZ + o0 + tx];
    }
    __syncthreads();
    bf16_t* dst = wet + (size_t)e * O_SZ * D_SZ;
#pragma unroll
    for (int i = 0; i < 16; ++i) {
      int o = ty + i * 4;
      dst[(size_t)(o0 + o) * D_SZ + d0 + tx] = (bf16_t)tile[tx][o];
    }
  }
}

// ---------------- fused expert GEMM + gate combine ----------------
// R3 structure (8 waves, 64x64 tiles, ring-3 A, counted vmcnt) with ONE change:
// B fragments are loaded DIRECTLY from L1/L2 (wet window is 16KB/step, cached),
// removing B's ds_reads (64/step) and staging writes (16KB/step) from the LDS
// port, which was the measured floor (~1900 of 2870 cyc/step).
__device__ __forceinline__ void gl16(const bf16_t* g, const bf16_t* l) {
  __builtin_amdgcn_global_load_lds(
      (const __attribute__((address_space(1))) void*)g,
      (__attribute__((address_space(3))) void*)l, 16, 0, 0);
}

__global__ __launch_bounds__(512, 2) void moe_gemm(
    const bf16_t* __restrict__ xb,    // [B, D] bf16
    const bf16_t* __restrict__ wet,   // [E, O, D] bf16
    const float* __restrict__ gates,  // [B, E]
    const float* __restrict__ be,     // [E, O]
    float* __restrict__ out)          // [B, O]
{
  // ring-3 A buffers only; B comes straight from global (L1/L2-resident window)
  __shared__ bf16_t lA[3][BM * BK];   // 3 x 32 KB
  __shared__ float  lG[BM * 9];       // gates, padded stride 9
  __shared__ float  lBe[E_SZ * BN];   // be tile

  const int tid = threadIdx.x;
  const int w = tid >> 6, lane = tid & 63;

  // ---- XCD-locality remap (round 2: FETCH 533->97 MB) ----
  const int flat = blockIdx.x + (blockIdx.y << 3);  // gridDim.x == 8
  const int xcd = flat & 7, slot = flat >> 3;
  const int bt = (xcd << 2) + (slot & 3);  // b-tile 0..31
  const int ot = slot >> 2;                // o-tile 0..7
  const int b0 = bt * BM;
  const int o0 = ot * BN;

  const int wm = (w >> 1) * 64, wn = (w & 1) * 64;  // 4x2 wave grid, 64x64 per wave
  const int m16 = lane & 15, q = lane >> 4;

  // ---- prologue: gates + be into LDS ----
  {
    float4 g4 = ((const float4*)(gates + (size_t)b0 * 8))[tid];
    int gr = tid >> 1, gc = (tid & 1) * 4;
    lG[gr * 9 + gc + 0] = g4.x; lG[gr * 9 + gc + 1] = g4.y;
    lG[gr * 9 + gc + 2] = g4.z; lG[gr * 9 + gc + 3] = g4.w;
#pragma unroll
    for (int p = 0; p < 2; ++p) {
      int idx = tid + p * 512;
      lBe[idx] = be[(size_t)(idx >> 7) * O_SZ + o0 + (idx & 127)];
    }
  }

  // ---- A staging constants (identical to R3) ----
  // LDS dest linear; swizzle on the GLOBAL side: phys slot s at row r holds
  // logical slot s^(r&7); reads apply the same XOR.
  const bf16_t* aptr[4]; int aoffL[4];
#pragma unroll
  for (int j = 0; j < 4; ++j) {
    int g0 = w * 64 + 512 * j;            // wave-uniform base granule
    int row = (g0 >> 3) + (lane >> 3);    // 8 granules (128B) per 64-col row
    int ls = (lane & 7) ^ (row & 7);
    aptr[j] = xb + (size_t)(b0 + row) * D_SZ + ls * 8;
    aoffL[j] = g0 * 8;
  }

  // ---- hoisted per-lane LDS read byte-offsets for A ----
  const int xk = m16 & 7;
  const int offA0 = (wm + m16) * 128 + ((q ^ xk) << 4);
  const int offA1 = (wm + m16) * 128 + (((4 | q) ^ xk) << 4);

  // ---- per-lane B fragment element-offsets (loop-invariant) ----
  // b-frag h at (j): wet[(o0 + wn + j*16 + m16)*D + kc + q*8 + h*32]
  int bvoff[4];
#pragma unroll
  for (int j = 0; j < 4; ++j) bvoff[j] = (wn + j * 16 + m16) * D_SZ + q * 8;

  bf16x8 bfr[4][2];

#define LOADB(t_) do {                                                         \
    const bf16_t* bsrc_ = wet + (size_t)o0 * D_SZ +                            \
        (((size_t)((t_) >> 4)) << 20) + (((t_) & 15) << 6);                    \
    _Pragma("unroll")                                                          \
    for (int j = 0; j < 4; ++j) {                                              \
      bfr[j][0] = *(const bf16x8*)(bsrc_ + bvoff[j]);                          \
      bfr[j][1] = *(const bf16x8*)(bsrc_ + bvoff[j] + 32);                     \
    }                                                                          \
  } while (0)

#define STAGE(t_, buf_) do {                                                   \
    const int kk_ = ((t_) & 15) << 6;                                          \
    _Pragma("unroll")                                                          \
    for (int js = 0; js < 4; ++js) gl16(aptr[js] + kk_, &lA[buf_][0] + aoffL[js]); \
  } while (0)

  f32x4 acc[4][4], outAcc[4][4];
#pragma unroll
  for (int i = 0; i < 4; ++i)
#pragma unroll
    for (int j = 0; j < 4; ++j) {
      acc[i][j] = f32x4{0.f, 0.f, 0.f, 0.f};
      outAcc[i][j] = f32x4{0.f, 0.f, 0.f, 0.f};
    }

  STAGE(0, 0);
  STAGE(1, 1);
  // drain own lG/lBe ds_writes so the first loop barrier publishes them
  asm volatile("s_waitcnt lgkmcnt(0)" ::: "memory");

  // BODY: A from LDS, B from registers (LOADB'd this step).
  // Compiler's waits for bfr (vmcnt(11)..(4)) retire B loads while leaving the
  // A-stage of t+2 in flight (B was issued before the stage in program order,
  // and in-order retirement keeps older A stages correct either way).
#define BODY(cur_) do {                                                        \
    const char* la_ = (const char*)(&lA[cur_][0]);                             \
    bf16x8 a_[4];                                                              \
    _Pragma("unroll")                                                          \
    for (int i = 0; i < 4; ++i) a_[i] = *(const bf16x8*)(la_ + offA0 + i * 2048); \
    __builtin_amdgcn_s_setprio(1);                                             \
    _Pragma("unroll")                                                          \
    for (int i = 0; i < 4; ++i)                                                \
      _Pragma("unroll")                                                        \
      for (int j = 0; j < 4; ++j)                                              \
        acc[i][j] = __builtin_amdgcn_mfma_f32_16x16x32_bf16(                   \
            a_[i], bfr[j][0], acc[i][j], 0, 0, 0);                             \
    __builtin_amdgcn_s_setprio(0);                                             \
    _Pragma("unroll")                                                          \
    for (int i = 0; i < 4; ++i) a_[i] = *(const bf16x8*)(la_ + offA1 + i * 2048); \
    __builtin_amdgcn_s_setprio(1);                                             \
    _Pragma("unroll")                                                          \
    for (int i = 0; i < 4; ++i)                                                \
      _Pragma("unroll")                                                        \
      for (int j = 0; j < 4; ++j)                                              \
        acc[i][j] = __builtin_amdgcn_mfma_f32_16x16x32_bf16(                   \
            a_[i], bfr[j][1], acc[i][j], 0, 0, 0);                             \
    __builtin_amdgcn_s_setprio(0);                                             \
  } while (0)

  // C layout: col = lane&15, row = q*4+reg
#define COMBINE(e_) do {                                                       \
    float bec_[4];                                                             \
    _Pragma("unroll")                                                          \
    for (int j = 0; j < 4; ++j) bec_[j] = lBe[(e_) * BN + wn + j * 16 + m16];  \
    _Pragma("unroll")                                                          \
    for (int i = 0; i < 4; ++i) {                                              \
      _Pragma("unroll")                                                        \
      for (int rg = 0; rg < 4; ++rg) {                                         \
        float gv = lG[(wm + i * 16 + q * 4 + rg) * 9 + (e_)];                  \
        _Pragma("unroll")                                                      \
        for (int j = 0; j < 4; ++j) {                                          \
          outAcc[i][j][rg] += gv * (acc[i][j][rg] + bec_[j]);                  \
          acc[i][j][rg] = 0.f;                                                 \
        }                                                                      \
      }                                                                        \
    }                                                                          \
  } while (0)

  // steady state at the wait point: only the A-stage of t+1 (4 loads) remains
#define STEP_S(t_, cur_, nb_) do {                                             \
    asm volatile("s_waitcnt vmcnt(4)" ::: "memory");                           \
    __builtin_amdgcn_s_barrier();                                              \
    asm volatile("" ::: "memory");                                             \
    LOADB(t_);                                                                 \
    STAGE((t_) + 2, nb_);                                                      \
    BODY(cur_);                                                                \
    if (((t_) & 15) == 15) COMBINE((t_) >> 4);                                 \
  } while (0)

#pragma unroll 1
  for (int t3 = 0; t3 < 126; t3 += 3) {
    STEP_S(t3 + 0, 0, 2);
    STEP_S(t3 + 1, 1, 0);
    STEP_S(t3 + 2, 2, 1);
  }
  // t = 126: no stage (tiles 0..127 all staged)
  asm volatile("s_waitcnt vmcnt(4)" ::: "memory");
  __builtin_amdgcn_s_barrier();
  asm volatile("" ::: "memory");
  LOADB(126);
  BODY(0);
  // t = 127: final tile in buf 1
  asm volatile("s_waitcnt vmcnt(0)" ::: "memory");
  __builtin_amdgcn_s_barrier();
  asm volatile("" ::: "memory");
  LOADB(127);
  BODY(1);
  COMBINE(7);

  // ---- epilogue: store combined output ----
#pragma unroll
  for (int i = 0; i < 4; ++i)
#pragma unroll
    for (int rg = 0; rg < 4; ++rg) {
      float* orow = out + (size_t)(b0 + wm + i * 16 + q * 4 + rg) * O_SZ
                    + o0 + wn + m16;
#pragma unroll
      for (int j = 0; j < 4; ++j) orow[j * 16] = outAcc[i][j][rg];
    }
}

extern "C" void kernel_launch(void* const* d_in, const int* in_sizes, int n_in,
                              void* d_out, int out_size, void* d_ws, size_t ws_size,
                              hipStream_t stream) {
  const float* x  = (const float*)d_in[0];
  const float* Wg = (const float*)d_in[1];
  const float* bg = (const float*)d_in[2];
  const float* We = (const float*)d_in[3];
  const float* be = (const float*)d_in[4];
  float* out = (float*)d_out;

  char* ws = (char*)d_ws;
  float*  gates = (float*)ws;                             // 256 KB
  bf16_t* xb    = (bf16_t*)(ws + (1 << 18));              // 16 MB
  bf16_t* wet   = (bf16_t*)(ws + (1 << 18) + (1 << 24));  // 16 MB

  prep_kernel<<<4096, 256, 0, stream>>>(x, Wg, bg, We, gates, xb, wet);
  moe_gemm<<<dim3(O_SZ / BN, B_SZ / BM), 512, 0, stream>>>(xb, wet, gates, be, out);
}

// Round 7
// 435.923 us; speedup vs baseline: 1.0529x; 1.0529x over previous
//
#include <hip/hip_runtime.h>
#include <hip/hip_bf16.h>
#include <stdint.h>

#define B_SZ 8192
#define D_SZ 1024
#define O_SZ 1024
#define E_SZ 8

#define BM 256
#define BN 128
#define BK 64
#define NT 128  // virtual K-steps: E_SZ * (D_SZ / BK)

typedef __bf16 bf16_t;
typedef __bf16 bf16x8 __attribute__((ext_vector_type(8)));
typedef __bf16 bf16x4 __attribute__((ext_vector_type(4)));
typedef float  f32x4  __attribute__((ext_vector_type(4)));

// ---------------- merged prep: gating+cvt (blocks 0..2047) | We transpose (2048..4095) ----------------
__global__ __launch_bounds__(256) void prep_kernel(
    const float* __restrict__ x, const float* __restrict__ Wg,
    const float* __restrict__ bg, const float* __restrict__ We,
    float* __restrict__ gates, bf16_t* __restrict__ xb,
    bf16_t* __restrict__ wet) {
  __shared__ float tile[64][65];
  const int bid = blockIdx.x;
  if (bid < 2048) {
    // ---- gating: softmax(x @ Wg + bg) fused with x fp32->bf16 ----
    const int w = threadIdx.x >> 6, lane = threadIdx.x & 63;
    const int b = bid * 4 + w;
    const float4* xr = (const float4*)(x + (size_t)b * D_SZ);
    bf16x4* xbr = (bf16x4*)(xb + (size_t)b * D_SZ);
    float acc[8];
#pragma unroll
    for (int e = 0; e < 8; ++e) acc[e] = 0.f;
#pragma unroll 1
    for (int it = 0; it < 4; ++it) {
      int d4 = it * 64 + lane;  // float4 index; d = d4*4
      float4 v = xr[d4];
      bf16x4 ob;
      ob[0] = (bf16_t)v.x; ob[1] = (bf16_t)v.y;
      ob[2] = (bf16_t)v.z; ob[3] = (bf16_t)v.w;
      xbr[d4] = ob;
      const float4* wr = (const float4*)(Wg + (size_t)d4 * 32);  // 4 rows x 8
      float xs[4] = {v.x, v.y, v.z, v.w};
#pragma unroll
      for (int rr = 0; rr < 4; ++rr) {
        float4 wa = wr[rr * 2], wb = wr[rr * 2 + 1];
        acc[0] += xs[rr] * wa.x; acc[1] += xs[rr] * wa.y;
        acc[2] += xs[rr] * wa.z; acc[3] += xs[rr] * wa.w;
        acc[4] += xs[rr] * wb.x; acc[5] += xs[rr] * wb.y;
        acc[6] += xs[rr] * wb.z; acc[7] += xs[rr] * wb.w;
      }
    }
#pragma unroll
    for (int off = 32; off >= 1; off >>= 1) {
#pragma unroll
      for (int e = 0; e < 8; ++e) acc[e] += __shfl_xor(acc[e], off, 64);
    }
    if (lane == 0) {
#pragma unroll
      for (int e = 0; e < 8; ++e) acc[e] += bg[e];
      float m = acc[0];
#pragma unroll
      for (int e = 1; e < 8; ++e) m = fmaxf(m, acc[e]);
      float s = 0.f, ex[8];
#pragma unroll
      for (int e = 0; e < 8; ++e) { ex[e] = __expf(acc[e] - m); s += ex[e]; }
      float inv = 1.0f / s;
      float* gr = gates + (size_t)b * 8;
#pragma unroll
      for (int e = 0; e < 8; ++e) gr[e] = ex[e] * inv;
    }
  } else {
    // ---- We [E,D,O] fp32 -> WeT [E,O,D] bf16 ----
    const int bt = bid - 2048;
    const int e = bt >> 8;
    const int d0 = ((bt >> 4) & 15) * 64, o0 = (bt & 15) * 64;
    const int tx = threadIdx.x & 63, ty = threadIdx.x >> 6;
    const float* src = We + (size_t)e * D_SZ * O_SZ;
#pragma unroll
    for (int i = 0; i < 16; ++i) {
      int d = ty + i * 4;
      tile[d][tx] = src[(size_t)(d0 + d) * O_SZ + o0 + tx];
    }
    __syncthreads();
    bf16_t* dst = wet + (size_t)e * O_SZ * D_SZ;
#pragma unroll
    for (int i = 0; i < 16; ++i) {
      int o = ty + i * 4;
      dst[(size_t)(o0 + o) * D_SZ + d0 + tx] = (bf16_t)tile[tx][o];
    }
  }
}

// ---------------- fused expert GEMM + gate combine ----------------
// R6 structure (A in ring-3 LDS, B direct from global) + the missing pipeline
// stage: B fragments are DOUBLE-BUFFERED in registers — step t issues
// LOADB(t+1) and computes with B(t) loaded a full step (~1600 cyc) earlier,
// hiding the L1/L2 gather latency that made R6 6514 cyc/step.
// vmcnt invariant: exactly 12 vmem ops issued per step (8 B + 4 A-stage), so
// vmcnt(12) at the wait point retires STAGE(t) and older precisely.
__device__ __forceinline__ void gl16(const bf16_t* g, const bf16_t* l) {
  __builtin_amdgcn_global_load_lds(
      (const __attribute__((address_space(1))) void*)g,
      (__attribute__((address_space(3))) void*)l, 16, 0, 0);
}

__global__ __launch_bounds__(512, 2) void moe_gemm(
    const bf16_t* __restrict__ xb,    // [B, D] bf16
    const bf16_t* __restrict__ wet,   // [E, O, D] bf16
    const float* __restrict__ gates,  // [B, E]
    const float* __restrict__ be,     // [E, O]
    float* __restrict__ out)          // [B, O]
{
  // ring-3 A buffers only; B comes straight from global (L1/L2-resident window)
  __shared__ bf16_t lA[3][BM * BK];   // 3 x 32 KB
  __shared__ float  lG[BM * 9];       // gates, padded stride 9
  __shared__ float  lBe[E_SZ * BN];   // be tile

  const int tid = threadIdx.x;
  const int w = tid >> 6, lane = tid & 63;

  // ---- XCD-locality remap (round 2: FETCH 533->97 MB) ----
  const int flat = blockIdx.x + (blockIdx.y << 3);  // gridDim.x == 8
  const int xcd = flat & 7, slot = flat >> 3;
  const int bt = (xcd << 2) + (slot & 3);  // b-tile 0..31
  const int ot = slot >> 2;                // o-tile 0..7
  const int b0 = bt * BM;
  const int o0 = ot * BN;

  const int wm = (w >> 1) * 64, wn = (w & 1) * 64;  // 4x2 wave grid, 64x64 per wave
  const int m16 = lane & 15, q = lane >> 4;

  // ---- prologue: gates + be into LDS ----
  {
    float4 g4 = ((const float4*)(gates + (size_t)b0 * 8))[tid];
    int gr = tid >> 1, gc = (tid & 1) * 4;
    lG[gr * 9 + gc + 0] = g4.x; lG[gr * 9 + gc + 1] = g4.y;
    lG[gr * 9 + gc + 2] = g4.z; lG[gr * 9 + gc + 3] = g4.w;
#pragma unroll
    for (int p = 0; p < 2; ++p) {
      int idx = tid + p * 512;
      lBe[idx] = be[(size_t)(idx >> 7) * O_SZ + o0 + (idx & 127)];
    }
  }

  // ---- A staging constants (identical to R3) ----
  // LDS dest linear; swizzle on the GLOBAL side: phys slot s at row r holds
  // logical slot s^(r&7); reads apply the same XOR.
  const bf16_t* aptr[4]; int aoffL[4];
#pragma unroll
  for (int j = 0; j < 4; ++j) {
    int g0 = w * 64 + 512 * j;            // wave-uniform base granule
    int row = (g0 >> 3) + (lane >> 3);    // 8 granules (128B) per 64-col row
    int ls = (lane & 7) ^ (row & 7);
    aptr[j] = xb + (size_t)(b0 + row) * D_SZ + ls * 8;
    aoffL[j] = g0 * 8;
  }

  // ---- hoisted per-lane LDS read byte-offsets for A ----
  const int xk = m16 & 7;
  const int offA0 = (wm + m16) * 128 + ((q ^ xk) << 4);
  const int offA1 = (wm + m16) * 128 + (((4 | q) ^ xk) << 4);

  // ---- per-lane B fragment element-offsets (loop-invariant) ----
  // b-frag h at (j): wet[(o0 + wn + j*16 + m16)*D + kc + q*8 + h*32]
  int bvoff[4];
#pragma unroll
  for (int j = 0; j < 4; ++j) bvoff[j] = (wn + j * 16 + m16) * D_SZ + q * 8;

  bf16x8 bfr0[4][2], bfr1[4][2];  // double-buffered B fragments

#define LOADB(t_, BF_) do {                                                    \
    const bf16_t* bsrc_ = wet + (size_t)o0 * D_SZ +                            \
        (((size_t)((t_) >> 4)) << 20) + (((t_) & 15) << 6);                    \
    _Pragma("unroll")                                                          \
    for (int j = 0; j < 4; ++j) {                                              \
      BF_[j][0] = *(const bf16x8*)(bsrc_ + bvoff[j]);                          \
      BF_[j][1] = *(const bf16x8*)(bsrc_ + bvoff[j] + 32);                     \
    }                                                                          \
  } while (0)

#define STAGE(t_, buf_) do {                                                   \
    const int kk_ = ((t_) & 15) << 6;                                          \
    _Pragma("unroll")                                                          \
    for (int js = 0; js < 4; ++js) gl16(aptr[js] + kk_, &lA[buf_][0] + aoffL[js]); \
  } while (0)

  f32x4 acc[4][4], outAcc[4][4];
#pragma unroll
  for (int i = 0; i < 4; ++i)
#pragma unroll
    for (int j = 0; j < 4; ++j) {
      acc[i][j] = f32x4{0.f, 0.f, 0.f, 0.f};
      outAcc[i][j] = f32x4{0.f, 0.f, 0.f, 0.f};
    }

  STAGE(0, 0);
  STAGE(1, 1);
  LOADB(0, bfr0);  // prologue: 12 vmem ops outstanding = steady state
  // drain own lG/lBe ds_writes so the first loop barrier publishes them
  asm volatile("s_waitcnt lgkmcnt(0)" ::: "memory");

  // BODY: A from LDS, B from registers (prefetched LAST step).
#define BODY(cur_, BF_) do {                                                   \
    const char* la_ = (const char*)(&lA[cur_][0]);                             \
    bf16x8 a_[4];                                                              \
    _Pragma("unroll")                                                          \
    for (int i = 0; i < 4; ++i) a_[i] = *(const bf16x8*)(la_ + offA0 + i * 2048); \
    __builtin_amdgcn_s_setprio(1);                                             \
    _Pragma("unroll")                                                          \
    for (int i = 0; i < 4; ++i)                                                \
      _Pragma("unroll")                                                        \
      for (int j = 0; j < 4; ++j)                                              \
        acc[i][j] = __builtin_amdgcn_mfma_f32_16x16x32_bf16(                   \
            a_[i], BF_[j][0], acc[i][j], 0, 0, 0);                             \
    __builtin_amdgcn_s_setprio(0);                                             \
    _Pragma("unroll")                                                          \
    for (int i = 0; i < 4; ++i) a_[i] = *(const bf16x8*)(la_ + offA1 + i * 2048); \
    __builtin_amdgcn_s_setprio(1);                                             \
    _Pragma("unroll")                                                          \
    for (int i = 0; i < 4; ++i)                                                \
      _Pragma("unroll")                                                        \
      for (int j = 0; j < 4; ++j)                                              \
        acc[i][j] = __builtin_amdgcn_mfma_f32_16x16x32_bf16(                   \
            a_[i], BF_[j][1], acc[i][j], 0, 0, 0);                             \
    __builtin_amdgcn_s_setprio(0);                                             \
  } while (0)

  // C layout: col = lane&15, row = q*4+reg
#define COMBINE(e_) do {                                                       \
    float bec_[4];                                                             \
    _Pragma("unroll")                                                          \
    for (int j = 0; j < 4; ++j) bec_[j] = lBe[(e_) * BN + wn + j * 16 + m16];  \
    _Pragma("unroll")                                                          \
    for (int i = 0; i < 4; ++i) {                                              \
      _Pragma("unroll")                                                        \
      for (int rg = 0; rg < 4; ++rg) {                                         \
        float gv = lG[(wm + i * 16 + q * 4 + rg) * 9 + (e_)];                  \
        _Pragma("unroll")                                                      \
        for (int j = 0; j < 4; ++j) {                                          \
          outAcc[i][j][rg] += gv * (acc[i][j][rg] + bec_[j]);                  \
          acc[i][j][rg] = 0.f;                                                 \
        }                                                                      \
      }                                                                        \
    }                                                                          \
  } while (0)

  // step t: wait (youngest 12 = LOADB(t)+STAGE(t+1) stay in flight), barrier,
  // issue LOADB(t+1) into spare buffer, STAGE(t+2), compute with B(t).
#define STEP_S(t_, cur_, nb_, BC_, BN_) do {                                   \
    asm volatile("s_waitcnt vmcnt(12)" ::: "memory");                          \
    __builtin_amdgcn_s_barrier();                                              \
    asm volatile("" ::: "memory");                                             \
    LOADB((t_) + 1, BN_);                                                      \
    STAGE((t_) + 2, nb_);                                                      \
    BODY(cur_, BC_);                                                           \
    if (((t_) & 15) == 15) COMBINE((t_) >> 4);                                 \
  } while (0)

  // 6-step unroll: ring-3 (A bufs) x parity-2 (B reg bufs); 126 = 21 x 6
#pragma unroll 1
  for (int t6 = 0; t6 < 126; t6 += 6) {
    STEP_S(t6 + 0, 0, 2, bfr0, bfr1);
    STEP_S(t6 + 1, 1, 0, bfr1, bfr0);
    STEP_S(t6 + 2, 2, 1, bfr0, bfr1);
    STEP_S(t6 + 3, 0, 2, bfr1, bfr0);
    STEP_S(t6 + 4, 1, 0, bfr0, bfr1);
    STEP_S(t6 + 5, 2, 1, bfr1, bfr0);
  }
  // t = 126 (even: uses bfr0): all A staged; still prefetch final B(127)
  asm volatile("s_waitcnt vmcnt(12)" ::: "memory");
  __builtin_amdgcn_s_barrier();
  asm volatile("" ::: "memory");
  LOADB(127, bfr1);
  BODY(0, bfr0);
  // t = 127 (odd: uses bfr1)
  asm volatile("s_waitcnt vmcnt(0)" ::: "memory");
  __builtin_amdgcn_s_barrier();
  asm volatile("" ::: "memory");
  BODY(1, bfr1);
  COMBINE(7);

  // ---- epilogue: store combined output ----
#pragma unroll
  for (int i = 0; i < 4; ++i)
#pragma unroll
    for (int rg = 0; rg < 4; ++rg) {
      float* orow = out + (size_t)(b0 + wm + i * 16 + q * 4 + rg) * O_SZ
                    + o0 + wn + m16;
#pragma unroll
      for (int j = 0; j < 4; ++j) orow[j * 16] = outAcc[i][j][rg];
    }
}

extern "C" void kernel_launch(void* const* d_in, const int* in_sizes, int n_in,
                              void* d_out, int out_size, void* d_ws, size_t ws_size,
                              hipStream_t stream) {
  const float* x  = (const float*)d_in[0];
  const float* Wg = (const float*)d_in[1];
  const float* bg = (const float*)d_in[2];
  const float* We = (const float*)d_in[3];
  const float* be = (const float*)d_in[4];
  float* out = (float*)d_out;

  char* ws = (char*)d_ws;
  float*  gates = (float*)ws;                             // 256 KB
  bf16_t* xb    = (bf16_t*)(ws + (1 << 18));              // 16 MB
  bf16_t* wet   = (bf16_t*)(ws + (1 << 18) + (1 << 24));  // 16 MB

  prep_kernel<<<4096, 256, 0, stream>>>(x, Wg, bg, We, gates, xb, wet);
  moe_gemm<<<dim3(O_SZ / BN, B_SZ / BM), 512, 0, stream>>>(xb, wet, gates, be, out);
}

// Round 8
// 327.964 us; speedup vs baseline: 1.3995x; 1.3292x over previous
//
#include <hip/hip_runtime.h>
#include <hip/hip_bf16.h>
#include <stdint.h>

#define B_SZ 8192
#define D_SZ 1024
#define O_SZ 1024
#define E_SZ 8

#define BM 256
#define BN 128
#define BK 64
#define NT 128  // virtual K-steps: E_SZ * (D_SZ / BK)

typedef __bf16 bf16_t;
typedef __bf16 bf16x8 __attribute__((ext_vector_type(8)));
typedef __bf16 bf16x4 __attribute__((ext_vector_type(4)));
typedef float  f32x4  __attribute__((ext_vector_type(4)));

// ---------------- merged prep: gating+cvt (blocks 0..2047) | We repack (2048..4095) ----------------
// We [E,D,O] fp32 -> wet PACKED bf16, fragment-major so moe_gemm's B loads are
// lane-contiguous 1KB bursts (R7's 2KB-strided gathers aliased L1 sets and
// serialized the TA at ~50cyc/instr -> MfmaUtil 17%).
// Packed index: e<<20 | ot<<17 | t16<<13 | half<<12 | j<<10 | h<<9 | m16<<5 | q<<3 | elem
//   where o = ot*128 + half*64 + j*16 + m16,  d = t16*64 + h*32 + q*8 + elem.
__global__ __launch_bounds__(256) void prep_kernel(
    const float* __restrict__ x, const float* __restrict__ Wg,
    const float* __restrict__ bg, const float* __restrict__ We,
    float* __restrict__ gates, bf16_t* __restrict__ xb,
    bf16_t* __restrict__ wet) {
  __shared__ float tile[64][65];
  const int bid = blockIdx.x;
  if (bid < 2048) {
    // ---- gating: softmax(x @ Wg + bg) fused with x fp32->bf16 ----
    const int w = threadIdx.x >> 6, lane = threadIdx.x & 63;
    const int b = bid * 4 + w;
    const float4* xr = (const float4*)(x + (size_t)b * D_SZ);
    bf16x4* xbr = (bf16x4*)(xb + (size_t)b * D_SZ);
    float acc[8];
#pragma unroll
    for (int e = 0; e < 8; ++e) acc[e] = 0.f;
#pragma unroll 1
    for (int it = 0; it < 4; ++it) {
      int d4 = it * 64 + lane;  // float4 index; d = d4*4
      float4 v = xr[d4];
      bf16x4 ob;
      ob[0] = (bf16_t)v.x; ob[1] = (bf16_t)v.y;
      ob[2] = (bf16_t)v.z; ob[3] = (bf16_t)v.w;
      xbr[d4] = ob;
      const float4* wr = (const float4*)(Wg + (size_t)d4 * 32);  // 4 rows x 8
      float xs[4] = {v.x, v.y, v.z, v.w};
#pragma unroll
      for (int rr = 0; rr < 4; ++rr) {
        float4 wa = wr[rr * 2], wb = wr[rr * 2 + 1];
        acc[0] += xs[rr] * wa.x; acc[1] += xs[rr] * wa.y;
        acc[2] += xs[rr] * wa.z; acc[3] += xs[rr] * wa.w;
        acc[4] += xs[rr] * wb.x; acc[5] += xs[rr] * wb.y;
        acc[6] += xs[rr] * wb.z; acc[7] += xs[rr] * wb.w;
      }
    }
#pragma unroll
    for (int off = 32; off >= 1; off >>= 1) {
#pragma unroll
      for (int e = 0; e < 8; ++e) acc[e] += __shfl_xor(acc[e], off, 64);
    }
    if (lane == 0) {
#pragma unroll
      for (int e = 0; e < 8; ++e) acc[e] += bg[e];
      float m = acc[0];
#pragma unroll
      for (int e = 1; e < 8; ++e) m = fmaxf(m, acc[e]);
      float s = 0.f, ex[8];
#pragma unroll
      for (int e = 0; e < 8; ++e) { ex[e] = __expf(acc[e] - m); s += ex[e]; }
      float inv = 1.0f / s;
      float* gr = gates + (size_t)b * 8;
#pragma unroll
      for (int e = 0; e < 8; ++e) gr[e] = ex[e] * inv;
    }
  } else {
    // ---- We [E,D,O] fp32 -> packed wet bf16 ----
    const int bt = bid - 2048;
    const int e = bt >> 8;
    const int d0 = ((bt >> 4) & 15) * 64, o0 = (bt & 15) * 64;
    const int tx = threadIdx.x & 63, ty = threadIdx.x >> 6;
    const float* src = We + (size_t)e * D_SZ * O_SZ;
#pragma unroll
    for (int i = 0; i < 16; ++i) {
      int d = ty + i * 4;
      tile[d][tx] = src[(size_t)(d0 + d) * O_SZ + o0 + tx];
    }
    __syncthreads();
    // tile[dd][oo] = We[e][d0+dd][o0+oo]; write packed(e, o0+oo, d0+tx)
    bf16_t* dst = wet + (((size_t)e) << 20) + (((size_t)(o0 >> 7)) << 17)
                  + ((d0 >> 6) << 13) + (((o0 >> 6) & 1) << 12);
    const int lo = ((tx >> 5) << 9) | (((tx >> 3) & 3) << 3) | (tx & 7);
#pragma unroll
    for (int i = 0; i < 16; ++i) {
      int oo = ty + i * 4;
      dst[((oo >> 4) << 10) | ((oo & 15) << 5) | lo] = (bf16_t)tile[tx][oo];
    }
  }
}

// ---------------- fused expert GEMM + gate combine ----------------
// A in ring-3 LDS (gl16), B direct-to-VGPR from PACKED wet (contiguous 1KB
// per instruction), double-buffered in registers one step ahead.
// vmcnt: exactly 12 vmem ops issued per step (8 B + 4 A-stage); vmcnt(12) at
// step top retires STAGE(t) precisely while keeping LOADB(t)+STAGE(t+1) aloft.
__device__ __forceinline__ void gl16(const bf16_t* g, const bf16_t* l) {
  __builtin_amdgcn_global_load_lds(
      (const __attribute__((address_space(1))) void*)g,
      (__attribute__((address_space(3))) void*)l, 16, 0, 0);
}

__global__ __launch_bounds__(512, 2) void moe_gemm(
    const bf16_t* __restrict__ xb,    // [B, D] bf16
    const bf16_t* __restrict__ wet,   // packed, see prep_kernel
    const float* __restrict__ gates,  // [B, E]
    const float* __restrict__ be,     // [E, O]
    float* __restrict__ out)          // [B, O]
{
  __shared__ bf16_t lA[3][BM * BK];   // 3 x 32 KB
  __shared__ float  lG[BM * 9];       // gates, padded stride 9
  __shared__ float  lBe[E_SZ * BN];   // be tile

  const int tid = threadIdx.x;
  const int w = tid >> 6, lane = tid & 63;

  // ---- XCD-locality remap (round 2: FETCH 533->97 MB) ----
  const int flat = blockIdx.x + (blockIdx.y << 3);  // gridDim.x == 8
  const int xcd = flat & 7, slot = flat >> 3;
  const int bt = (xcd << 2) + (slot & 3);  // b-tile 0..31
  const int ot = slot >> 2;                // o-tile 0..7
  const int b0 = bt * BM;
  const int o0 = ot * BN;

  const int wm = (w >> 1) * 64, wn = (w & 1) * 64;  // 4x2 wave grid, 64x64 per wave
  const int m16 = lane & 15, q = lane >> 4;

  // ---- prologue: gates + be into LDS ----
  {
    float4 g4 = ((const float4*)(gates + (size_t)b0 * 8))[tid];
    int gr = tid >> 1, gc = (tid & 1) * 4;
    lG[gr * 9 + gc + 0] = g4.x; lG[gr * 9 + gc + 1] = g4.y;
    lG[gr * 9 + gc + 2] = g4.z; lG[gr * 9 + gc + 3] = g4.w;
#pragma unroll
    for (int p = 0; p < 2; ++p) {
      int idx = tid + p * 512;
      lBe[idx] = be[(size_t)(idx >> 7) * O_SZ + o0 + (idx & 127)];
    }
  }

  // ---- A staging constants (identical to R3) ----
  // LDS dest linear; swizzle on the GLOBAL side: phys slot s at row r holds
  // logical slot s^(r&7); reads apply the same XOR.
  const bf16_t* aptr[4]; int aoffL[4];
#pragma unroll
  for (int j = 0; j < 4; ++j) {
    int g0 = w * 64 + 512 * j;            // wave-uniform base granule
    int row = (g0 >> 3) + (lane >> 3);    // 8 granules (128B) per 64-col row
    int ls = (lane & 7) ^ (row & 7);
    aptr[j] = xb + (size_t)(b0 + row) * D_SZ + ls * 8;
    aoffL[j] = g0 * 8;
  }

  // ---- hoisted per-lane LDS read byte-offsets for A ----
  const int xk = m16 & 7;
  const int offA0 = (wm + m16) * 128 + ((q ^ xk) << 4);
  const int offA1 = (wm + m16) * 128 + (((4 | q) ^ xk) << 4);

  // ---- packed-B addressing (loop-invariant) ----
  // wave's slice: ot (block), half = w&1 (wn); per (j,h): lane elem-offset
  // j<<10 | h<<9 | m16<<5 | q<<3  -> 64 lanes = contiguous 1KB.
  const bf16_t* bbase = wet + (((size_t)ot) << 17) + ((size_t)(w & 1) << 12);
  int bloff[4];
#pragma unroll
  for (int j = 0; j < 4; ++j) bloff[j] = (j << 10) | (m16 << 5) | (q << 3);

  bf16x8 bfr0[4][2], bfr1[4][2];  // double-buffered B fragments

#define LOADB(t_, BF_) do {                                                    \
    const bf16_t* bsrc_ = bbase + (((size_t)((t_) >> 4)) << 20)                \
                          + (((t_) & 15) << 13);                               \
    _Pragma("unroll")                                                          \
    for (int j = 0; j < 4; ++j) {                                              \
      BF_[j][0] = *(const bf16x8*)(bsrc_ + bloff[j]);                          \
      BF_[j][1] = *(const bf16x8*)(bsrc_ + bloff[j] + 512);                    \
    }                                                                          \
  } while (0)

#define STAGE(t_, buf_) do {                                                   \
    const int kk_ = ((t_) & 15) << 6;                                          \
    _Pragma("unroll")                                                          \
    for (int js = 0; js < 4; ++js) gl16(aptr[js] + kk_, &lA[buf_][0] + aoffL[js]); \
  } while (0)

  f32x4 acc[4][4], outAcc[4][4];
#pragma unroll
  for (int i = 0; i < 4; ++i)
#pragma unroll
    for (int j = 0; j < 4; ++j) {
      acc[i][j] = f32x4{0.f, 0.f, 0.f, 0.f};
      outAcc[i][j] = f32x4{0.f, 0.f, 0.f, 0.f};
    }

  STAGE(0, 0);
  STAGE(1, 1);
  LOADB(0, bfr0);  // prologue: 12 vmem ops outstanding = steady state
  // drain own lG/lBe ds_writes so the first loop barrier publishes them
  asm volatile("s_waitcnt lgkmcnt(0)" ::: "memory");

  // BODY: A from LDS, B from registers (prefetched LAST step).
#define BODY(cur_, BF_) do {                                                   \
    const char* la_ = (const char*)(&lA[cur_][0]);                             \
    bf16x8 a_[4];                                                              \
    _Pragma("unroll")                                                          \
    for (int i = 0; i < 4; ++i) a_[i] = *(const bf16x8*)(la_ + offA0 + i * 2048); \
    __builtin_amdgcn_s_setprio(1);                                             \
    _Pragma("unroll")                                                          \
    for (int i = 0; i < 4; ++i)                                                \
      _Pragma("unroll")                                                        \
      for (int j = 0; j < 4; ++j)                                              \
        acc[i][j] = __builtin_amdgcn_mfma_f32_16x16x32_bf16(                   \
            a_[i], BF_[j][0], acc[i][j], 0, 0, 0);                             \
    __builtin_amdgcn_s_setprio(0);                                             \
    _Pragma("unroll")                                                          \
    for (int i = 0; i < 4; ++i) a_[i] = *(const bf16x8*)(la_ + offA1 + i * 2048); \
    __builtin_amdgcn_s_setprio(1);                                             \
    _Pragma("unroll")                                                          \
    for (int i = 0; i < 4; ++i)                                                \
      _Pragma("unroll")                                                        \
      for (int j = 0; j < 4; ++j)                                              \
        acc[i][j] = __builtin_amdgcn_mfma_f32_16x16x32_bf16(                   \
            a_[i], BF_[j][1], acc[i][j], 0, 0, 0);                             \
    __builtin_amdgcn_s_setprio(0);                                             \
  } while (0)

  // C layout: col = lane&15, row = q*4+reg
#define COMBINE(e_) do {                                                       \
    float bec_[4];                                                             \
    _Pragma("unroll")                                                          \
    for (int j = 0; j < 4; ++j) bec_[j] = lBe[(e_) * BN + wn + j * 16 + m16];  \
    _Pragma("unroll")                                                          \
    for (int i = 0; i < 4; ++i) {                                              \
      _Pragma("unroll")                                                        \
      for (int rg = 0; rg < 4; ++rg) {                                         \
        float gv = lG[(wm + i * 16 + q * 4 + rg) * 9 + (e_)];                  \
        _Pragma("unroll")                                                      \
        for (int j = 0; j < 4; ++j) {                                          \
          outAcc[i][j][rg] += gv * (acc[i][j][rg] + bec_[j]);                  \
          acc[i][j][rg] = 0.f;                                                 \
        }                                                                      \
      }                                                                        \
    }                                                                          \
  } while (0)

  // step t: wait (retires STAGE(t); LOADB(t)+STAGE(t+1) stay aloft), barrier,
  // issue LOADB(t+1) into spare buffer, STAGE(t+2), compute with B(t).
#define STEP_S(t_, cur_, nb_, BC_, BN_) do {                                   \
    asm volatile("s_waitcnt vmcnt(12)" ::: "memory");                          \
    __builtin_amdgcn_s_barrier();                                              \
    asm volatile("" ::: "memory");                                             \
    LOADB((t_) + 1, BN_);                                                      \
    STAGE((t_) + 2, nb_);                                                      \
    BODY(cur_, BC_);                                                           \
    if (((t_) & 15) == 15) COMBINE((t_) >> 4);                                 \
  } while (0)

  // 6-step unroll: ring-3 (A bufs) x parity-2 (B reg bufs); 126 = 21 x 6
#pragma unroll 1
  for (int t6 = 0; t6 < 126; t6 += 6) {
    STEP_S(t6 + 0, 0, 2, bfr0, bfr1);
    STEP_S(t6 + 1, 1, 0, bfr1, bfr0);
    STEP_S(t6 + 2, 2, 1, bfr0, bfr1);
    STEP_S(t6 + 3, 0, 2, bfr1, bfr0);
    STEP_S(t6 + 4, 1, 0, bfr0, bfr1);
    STEP_S(t6 + 5, 2, 1, bfr1, bfr0);
  }
  // t = 126 (even: uses bfr0): all A staged; still prefetch final B(127)
  asm volatile("s_waitcnt vmcnt(12)" ::: "memory");
  __builtin_amdgcn_s_barrier();
  asm volatile("" ::: "memory");
  LOADB(127, bfr1);
  BODY(0, bfr0);
  // t = 127 (odd: uses bfr1)
  asm volatile("s_waitcnt vmcnt(0)" ::: "memory");
  __builtin_amdgcn_s_barrier();
  asm volatile("" ::: "memory");
  BODY(1, bfr1);
  COMBINE(7);

  // ---- epilogue: store combined output ----
#pragma unroll
  for (int i = 0; i < 4; ++i)
#pragma unroll
    for (int rg = 0; rg < 4; ++rg) {
      float* orow = out + (size_t)(b0 + wm + i * 16 + q * 4 + rg) * O_SZ
                    + o0 + wn + m16;
#pragma unroll
      for (int j = 0; j < 4; ++j) orow[j * 16] = outAcc[i][j][rg];
    }
}

extern "C" void kernel_launch(void* const* d_in, const int* in_sizes, int n_in,
                              void* d_out, int out_size, void* d_ws, size_t ws_size,
                              hipStream_t stream) {
  const float* x  = (const float*)d_in[0];
  const float* Wg = (const float*)d_in[1];
  const float* bg = (const float*)d_in[2];
  const float* We = (const float*)d_in[3];
  const float* be = (const float*)d_in[4];
  float* out = (float*)d_out;

  char* ws = (char*)d_ws;
  float*  gates = (float*)ws;                             // 256 KB
  bf16_t* xb    = (bf16_t*)(ws + (1 << 18));              // 16 MB
  bf16_t* wet   = (bf16_t*)(ws + (1 << 18) + (1 << 24));  // 16 MB (packed)

  prep_kernel<<<4096, 256, 0, stream>>>(x, Wg, bg, We, gates, xb, wet);
  moe_gemm<<<dim3(O_SZ / BN, B_SZ / BM), 512, 0, stream>>>(xb, wet, gates, be, out);
}